// Round 17
// baseline (287.073 us; speedup 1.0000x reference)
//
#include <hip/hip_runtime.h>
#include <hip/hip_bf16.h>
#include <hip/hip_fp16.h>

typedef _Float16 half8 __attribute__((ext_vector_type(8)));
typedef _Float16 half4 __attribute__((ext_vector_type(4)));
typedef float    floatx4 __attribute__((ext_vector_type(4)));

#define BM 64

// ---------------------------------------------------------------------------
// Kernel 1: W in MFMA-fragment order (unchanged).
// ---------------------------------------------------------------------------
__global__ void make_weights_frag(const float* __restrict__ p0, const float* __restrict__ p1,
                                  const float* __restrict__ p2, const float* __restrict__ p3,
                                  _Float16* __restrict__ wt) {
    int idx  = blockIdx.x * blockDim.x + threadIdx.x;   // 0 .. 24575
    int lane = idx & 63;
    int nf   = (idx >> 6) & 3;
    int s    = (idx >> 8) & 7;
    int wc   = (idx >> 11) & 3;
    int l    = idx >> 13;
    int n  = wc * 64 + nf * 16 + (lane & 15);
    int k0 = s * 32 + (lane >> 4) * 8;
    const float* P[4] = {p0, p1, p2, p3};
    const float* pb = P[l + 1] + n * 20;
    float pbr[20];
    #pragma unroll
    for (int i = 0; i < 20; ++i) pbr[i] = pb[i];
    half8 o;
    #pragma unroll
    for (int j = 0; j < 8; ++j) {
        const float* pa = P[l] + (k0 + j) * 20;
        float d2 = 0.f;
        #pragma unroll
        for (int i = 0; i < 20; ++i) { float df = pa[i] - pbr[i]; d2 += df * df; }
        float d = sqrtf(d2);
        float m = fmodf(d, 0.2f);
        o[j] = (_Float16)(10.0f * (0.05f - fabsf(m - 0.1f)) * 0.0625f);
    }
    *reinterpret_cast<half8*>(wt + (size_t)idx * 8) = o;
}

// keep-alive: prevents DCE of a loaded value without cost (rule #17)
struct U4 { unsigned a, b, c, d; };
__device__ __forceinline__ void keep(const half8& v) {
    U4 u = __builtin_bit_cast(U4, v);
    asm volatile("" :: "v"(u.a), "v"(u.b), "v"(u.c), "v"(u.d));
}

// ---------------------------------------------------------------------------
// Kernel 2: ABLATION, V0 == exact R14-proven kernel (depth-1 W dbuf).
//   VAR=0 FULL | VAR=1 no W loads (consume bb[0] always) |
//   VAR=2 no K-loop ds_reads (a = reg copies) | VAR=3 no MFMA (keep() loads).
//   Identical stage/epilogue/barrier structure in all variants.
// ---------------------------------------------------------------------------
template<int VAR>
__global__ __launch_bounds__(512, 4) void pcn_fused(
    const float* __restrict__ x, const _Float16* __restrict__ wt,
    const float* __restrict__ b1, const float* __restrict__ b2,
    const float* __restrict__ b3, float* __restrict__ out) {

    // z[row][k]: byte = row*512 + ((k/8)^(row&7))*16 + (k&7)*2
    __shared__ __align__(16) _Float16 zlds[BM * 256];   // 32 KB, in-place

    const int t    = threadIdx.x;
    const int lane = t & 63;
    const int wv   = t >> 6;      // 0..7: column slice [wv*32, wv*32+32)
    const int l15  = lane & 15;
    const int lg   = lane >> 4;   // 0..3
    const size_t row0 = (size_t)blockIdx.x * BM;

    char* const zb = reinterpret_cast<char*>(zlds);

    half8   bb[2][2];
    floatx4 acc[2][4];

    auto wfrag = [&](int l, int s, int j) -> const half8* {
        return reinterpret_cast<const half8*>(
            wt + (((size_t)l * 4 + (wv >> 1)) << 14) + s * 2048
               + ((wv & 1) * 2 + j) * 512 + lane * 8);
    };

    // ---- stage x: 64x256 f32 -> fp16 swizzled. 8 float4/thread, 2 batches.
    #pragma unroll
    for (int b = 0; b < 2; ++b) {
        floatx4 xr[4];
        #pragma unroll
        for (int i = 0; i < 4; ++i) {
            int g   = (b * 4 + i) * 512 + t;
            int row = g >> 6, c4 = g & 63;
            xr[i] = *reinterpret_cast<const floatx4*>(x + (row0 + row) * 256 + c4 * 4);
        }
        #pragma unroll
        for (int i = 0; i < 4; ++i) {
            int g   = (b * 4 + i) * 512 + t;
            int row = g >> 6, c4 = g & 63;
            half4 h;
            h[0] = (_Float16)xr[i][0]; h[1] = (_Float16)xr[i][1];
            h[2] = (_Float16)xr[i][2]; h[3] = (_Float16)xr[i][3];
            int chunk = (c4 >> 1) ^ (row & 7);
            *reinterpret_cast<half4*>(zb + row * 512 + chunk * 16 + (c4 & 1) * 8) = h;
        }
    }
    // prefetch layer-0 step-0 W while x-writes drain
    #pragma unroll
    for (int j = 0; j < 2; ++j) bb[0][j] = *wfrag(0, 0, j);
    __syncthreads();

    #pragma unroll
    for (int l = 0; l < 3; ++l) {
        const float* bias = (l == 0) ? b1 : (l == 1) ? b2 : b3;

        #pragma unroll
        for (int j = 0; j < 2; ++j) {
            const floatx4 bv4 = *reinterpret_cast<const floatx4*>(
                bias + wv * 32 + j * 16 + lg * 4);
            #pragma unroll
            for (int mf = 0; mf < 4; ++mf)
                acc[j][mf] = bv4;
        }

        #pragma unroll
        for (int s = 0; s < 8; ++s) {            // K-step of 32
            if constexpr (VAR != 1) {
                if (s < 7) {
                    #pragma unroll
                    for (int j = 0; j < 2; ++j)
                        bb[(s + 1) & 1][j] = *wfrag(l, s + 1, j);
                }
            }
            const int vchunk = (s * 4 + lg) ^ (l15 & 7);
            half8 a[4];
            if constexpr (VAR != 2) {
                #pragma unroll
                for (int mf = 0; mf < 4; ++mf)
                    a[mf] = *reinterpret_cast<const half8*>(
                        zb + (mf * 16 + l15) * 512 + vchunk * 16);
            } else {
                #pragma unroll
                for (int mf = 0; mf < 4; ++mf)
                    a[mf] = bb[VAR == 1 ? 0 : (s & 1)][mf & 1];
            }
            if constexpr (VAR != 3) {
                #pragma unroll
                for (int j = 0; j < 2; ++j)
                    #pragma unroll
                    for (int mf = 0; mf < 4; ++mf)
                        acc[j][mf] = __builtin_amdgcn_mfma_f32_16x16x32_f16(
                            bb[VAR == 1 ? 0 : (s & 1)][j], a[mf],
                            acc[j][mf], 0, 0, 0);
            } else {
                #pragma unroll
                for (int mf = 0; mf < 4; ++mf) keep(a[mf]);
                keep(bb[s & 1][0]); keep(bb[s & 1][1]);
            }
        }

        // cross-layer W prefetch: issued before the barrier, drains under epi
        if constexpr (VAR != 1) {
            if (l < 2) {
                #pragma unroll
                for (int j = 0; j < 2; ++j) bb[0][j] = *wfrag(l + 1, 0, j);
            }
        }

        if (l < 2) {
            __syncthreads();   // all waves done READING zlds
            #pragma unroll
            for (int j = 0; j < 2; ++j) {
                const int k0 = wv * 32 + j * 16 + lg * 4;
                #pragma unroll
                for (int mf = 0; mf < 4; ++mf) {
                    const int m = mf * 16 + l15;
                    half4 h;
                    #pragma unroll
                    for (int r = 0; r < 4; ++r)
                        h[r] = (_Float16)fmaxf(acc[j][mf][r], 0.0f);
                    const int byte = m * 512 + (((k0 >> 3) ^ (m & 7)) << 4)
                                   + (k0 & 7) * 2;
                    *reinterpret_cast<half4*>(zb + byte) = h;
                }
            }
            __syncthreads();   // writes visible before next layer's reads
        } else {
            #pragma unroll
            for (int j = 0; j < 2; ++j) {
                const int n0 = wv * 32 + j * 16 + lg * 4;
                #pragma unroll
                for (int mf = 0; mf < 4; ++mf) {
                    const size_t m = row0 + mf * 16 + l15;
                    *reinterpret_cast<floatx4*>(out + m * 256 + n0) = acc[j][mf];
                }
            }
        }
    }
}

extern "C" void kernel_launch(void* const* d_in, const int* in_sizes, int n_in,
                              void* d_out, int out_size, void* d_ws, size_t ws_size,
                              hipStream_t stream) {
    const float* x  = (const float*)d_in[0];
    const float* p0 = (const float*)d_in[1];
    const float* p1 = (const float*)d_in[2];
    const float* p2 = (const float*)d_in[3];
    const float* p3 = (const float*)d_in[4];
    const float* b1 = (const float*)d_in[5];
    const float* b2 = (const float*)d_in[6];
    const float* b3 = (const float*)d_in[7];
    float* out = (float*)d_out;
    _Float16* wt = (_Float16*)d_ws;              // 384 KB

    const int B = in_sizes[0] / 256;             // 131072
    const int G = B / BM;

    make_weights_frag<<<96, 256, 0, stream>>>(p0, p1, p2, p3, wt);
    // ablation variants (outputs overwritten by FULL below; FULL runs LAST)
    pcn_fused<1><<<G, 512, 0, stream>>>(x, wt, b1, b2, b3, out);   // no W loads
    pcn_fused<2><<<G, 512, 0, stream>>>(x, wt, b1, b2, b3, out);   // no ds_reads
    pcn_fused<3><<<G, 512, 0, stream>>>(x, wt, b1, b2, b3, out);   // no MFMA
    pcn_fused<0><<<G, 512, 0, stream>>>(x, wt, b1, b2, b3, out);   // FULL (correct)
}